// Round 6
// baseline (5727.090 us; speedup 1.0000x reference)
//
#include <hip/hip_runtime.h>
#include <hip/hip_bf16.h>

// (B,C,H,G) = (4,128,8,64); F=4096, DH=16, 127 rings.
#define Bn 4
#define Cn 128
#define Fn 4096
#define NRINGS 127

typedef short bhalf4 __attribute__((ext_vector_type(4)));
typedef float f32x4  __attribute__((ext_vector_type(4)));

// workspace offsets (float-slot units)
#define OFF_K   1048576
#define OFF_V   2097152
#define OFF_PM  3145728
#define OFF_PL  3211264
#define OFF_PO  3276800
#define OFF_VA  4325376
#define OFF_KN  4325888

__device__ __forceinline__ ushort f2bf(float f) {
    __hip_bfloat16 h = __float2bfloat16(f);
    return *reinterpret_cast<ushort*>(&h);
}

// ---------------------------------------------------------------------------
// init: Q0bf/Kbf rows [b][h][col][16] bf16; Vbf transposed [b][h][d][col] bf16.
// W staged in LDS (+1-padded) per 32-c chunk: coalesced global, 2-way banks.
// grid = 256 (b x 64-col tiles), 512 thr.
// ---------------------------------------------------------------------------
__global__ __launch_bounds__(512, 2) void initQKV(
    const float* __restrict__ x, const float* __restrict__ Wq0,
    const float* __restrict__ Wk0, const float* __restrict__ Wv0,
    ushort* __restrict__ Q0bf, ushort* __restrict__ Kbf, ushort* __restrict__ Vbf)
{
    __shared__ float xs[Cn * 64];          // 32 KB
    __shared__ float Wls[3 * 128 * 33];    // 50.7 KB
    const int wg = blockIdx.x, t = threadIdx.x;
    const int b = wg >> 6, n0 = (wg & 63) << 6;
    for (int idx = t; idx < Cn * 64; idx += 512) {
        int c = idx >> 6, j = idx & 63;
        xs[idx] = x[(((b << 7) + c) << 12) + n0 + j];
    }
    const int o = t & 127, j0 = (t >> 7) << 4;
    float aq[16], ak[16], av[16];
#pragma unroll
    for (int k = 0; k < 16; ++k) { aq[k] = 0.f; ak[k] = 0.f; av[k] = 0.f; }

    for (int cc = 0; cc < 128; cc += 32) {
        __syncthreads();   // xs ready (first iter) / Wls reuse safe (later)
        for (int idx = t; idx < 128 * 32; idx += 512) {
            int oo = idx >> 5, jj = idx & 31;
            Wls[oo * 33 + jj]                = Wq0[(oo << 7) + cc + jj];
            Wls[128 * 33 + oo * 33 + jj]     = Wk0[(oo << 7) + cc + jj];
            Wls[2 * 128 * 33 + oo * 33 + jj] = Wv0[(oo << 7) + cc + jj];
        }
        __syncthreads();
        for (int c2 = 0; c2 < 32; ++c2) {
            float wq = Wls[o * 33 + c2];
            float wk = Wls[128 * 33 + o * 33 + c2];
            float wv = Wls[2 * 128 * 33 + o * 33 + c2];
            const float* xr = &xs[((cc + c2) << 6) + j0];
#pragma unroll
            for (int k = 0; k < 16; ++k) {
                float xv = xr[k];
                aq[k] += wq * xv; ak[k] += wk * xv; av[k] += wv * xv;
            }
        }
    }

    const int h = o >> 4, d = o & 15;
    const int bh = (b << 3) + h;
#pragma unroll
    for (int k = 0; k < 16; ++k) {
        int col = n0 + j0 + k;
        int qi = ((bh << 12) + col) * 16 + d;
        Q0bf[qi] = f2bf(aq[k]);
        Kbf[qi]  = f2bf(ak[k]);
    }
    uint vv[8];
#pragma unroll
    for (int k2 = 0; k2 < 8; ++k2)
        vv[k2] = (uint)f2bf(av[2*k2]) | ((uint)f2bf(av[2*k2+1]) << 16);
    uint4* dst = (uint4*)&Vbf[(((bh << 4) + d) << 12) + n0 + j0];
    dst[0] = make_uint4(vv[0], vv[1], vv[2], vv[3]);
    dst[1] = make_uint4(vv[4], vv[5], vv[6], vv[7]);
}

// ---------------------------------------------------------------------------
// Fused per-ring kernel: WG (b,h,sp of 512 keys), 512 thr = 8 waves. No K/V
// LDS staging: MFMA fragments are read straight from global (L2-hot).
//   phase A: combine ring r-1 (16 slice-partials) -> feats (h==0) + global
//            bf16 K/V row updates for cols in this WG's key range
//   phase B: MFMA flash ring r: wave w: qt=w&3, key-half kh=w>>2 (256 keys)
//            S^T = K.Q^T (16 MFMA), single-pass softmax, PV (16 MFMA).
// Same-WG A->B global RAW ordered by threadfence + syncthreads.
// ---------------------------------------------------------------------------
template<bool TAIL>
__global__ __launch_bounds__(512, 2) void fusedRing(
    const float* __restrict__ x, const float* __restrict__ Wk0,
    const float* __restrict__ Wv0, const int* __restrict__ rings,
    const int* __restrict__ rsz, const ushort* __restrict__ Q0bf,
    ushort* __restrict__ Kbf, ushort* __restrict__ Vbf,
    float* __restrict__ pm, float* __restrict__ pl, float* __restrict__ po,
    float* __restrict__ feats, int r)
{
    __shared__ float outc[4 * 128];
    __shared__ int colsC[64], colsF[64];
    __shared__ int ownIdx[64];
    __shared__ int ownCnt;

    const int t = threadIdx.x, wgid = blockIdx.x;
    const int b = wgid >> 6, h = (wgid >> 3) & 7, sp = wgid & 7;
    const int bh = (b << 3) + h;
    const int n  = TAIL ? 0 : rsz[r];
    const int np = (r > 0) ? rsz[r - 1] : 0;
    const int keybase = sp << 9;

    if (t < 64) colsC[t] = (r > 0 && t < np) ? rings[(r-1)*64 + t] : -1;
    else if (t < 128) { int q = t - 64; colsF[q] = (!TAIL && q < n) ? rings[r*64 + q] : 0; }
    if (t == 0) ownCnt = 0;
    __syncthreads();

    // ---------------- phase A: combine ring r-1 ----------------
    if (r > 0) {
        const int bufp = (r - 1) & 1;
        if (t < np) {
            int cq = colsC[t];
            if (cq >= keybase && cq < keybase + 512) {
                int slot = atomicAdd(&ownCnt, 1);
                ownIdx[slot] = t;
            }
        }
        __syncthreads();
        const int cnt = ownCnt;
        for (int base = 0; base < cnt; base += 4) {
            {   // merge 16 slice-partials: 512 thr = 4 col-slots x 128 channels
                int slot = t >> 7, c = t & 127;
                int ow = base + slot;
                if (ow < cnt) {
                    int j = ownIdx[ow];
                    int col = colsC[j];
                    int hh = c >> 4, dd = c & 15;
                    int p0 = ((bufp << 5) + (b << 3) + hh) * 1024 + j;
                    float mstar = -1e30f;
#pragma unroll
                    for (int s2 = 0; s2 < 16; ++s2)
                        mstar = fmaxf(mstar, pm[p0 + (s2 << 6)]);
                    float lstar = 0.f, osum = 0.f;
#pragma unroll
                    for (int s2 = 0; s2 < 16; ++s2) {
                        int pi = p0 + (s2 << 6);
                        float e = __expf(pm[pi] - mstar);
                        lstar += pl[pi] * e;
                        osum  += po[(pi << 4) + dd] * e;
                    }
                    float outv = osum / lstar + x[(((b << 7) + c) << 12) + col];
                    outc[(slot << 7) + c] = outv;
                    if (h == 0) feats[(((b << 7) + c) << 12) + col] = outv;
                }
            }
            __syncthreads();
            if (!TAIL) {   // K/V row GEMV: 4 slots x 32 tasks x 4 quarters
                int slot = t >> 7, rem = t & 127;
                int task = rem >> 2, quarter = rem & 3;
                int ow = base + slot;
                if (ow < cnt) {
                    int isV = task >> 4, dd = task & 15;
                    int col = colsC[ownIdx[ow]];
                    int row = (h << 4) + dd;
                    const float* W = isV ? Wv0 : Wk0;
                    const float* oc = &outc[slot << 7];
                    float acc = 0.f;
                    int c0 = quarter << 5;
#pragma unroll
                    for (int c2 = 0; c2 < 32; ++c2)
                        acc += W[(row << 7) + c0 + c2] * oc[c0 + c2];
                    acc += __shfl_xor(acc, 1);
                    acc += __shfl_xor(acc, 2);
                    if (quarter == 0) {
                        ushort bfv = f2bf(acc);
                        if (isV) Vbf[(((bh << 4) + dd) << 12) + col] = bfv;
                        else     Kbf[((bh << 12) + col) * 16 + dd] = bfv;
                    }
                }
            }
            __syncthreads();
        }
    }
    if (TAIL) return;

    __threadfence();     // make phase-A K/V stores visible to own loads
    __syncthreads();

    // ---------------- phase B: MFMA flash ring r ----------------
    const int w = t >> 6, lane = t & 63;
    const int qt = w & 3, kh = w >> 2;
    const int buf = r & 1;
    if (qt * 16 < n) {
        const int lm = lane & 15, lg = lane >> 4;
        const int cq = colsF[qt * 16 + lm];
        bhalf4 qf = *(const bhalf4*)&Q0bf[(((bh << 12) + cq) << 4) + (lg << 2)];
        const int key0 = keybase + (kh << 8);
        f32x4 sc[16];
#pragma unroll
        for (int kt = 0; kt < 16; ++kt) {
            bhalf4 kf = *(const bhalf4*)
                &Kbf[(((bh << 12) + key0 + (kt << 4) + lm) << 4) + (lg << 2)];
            f32x4 z = {0.f, 0.f, 0.f, 0.f};
            sc[kt] = __builtin_amdgcn_mfma_f32_16x16x16bf16_1k(kf, qf, z, 0, 0, 0);
        }
        float m = -1e30f;
#pragma unroll
        for (int kt = 0; kt < 16; ++kt)
            m = fmaxf(m, fmaxf(fmaxf(sc[kt][0], sc[kt][1]), fmaxf(sc[kt][2], sc[kt][3])));
        m = fmaxf(m, __shfl_xor(m, 16));
        m = fmaxf(m, __shfl_xor(m, 32));
        float lsum = 0.f;
        bhalf4 pf[16];
#pragma unroll
        for (int kt = 0; kt < 16; ++kt) {
            float p0 = __expf((sc[kt][0] - m) * 0.25f);
            float p1 = __expf((sc[kt][1] - m) * 0.25f);
            float p2 = __expf((sc[kt][2] - m) * 0.25f);
            float p3 = __expf((sc[kt][3] - m) * 0.25f);
            lsum += (p0 + p1) + (p2 + p3);
            bhalf4 pv;
            pv[0] = (short)f2bf(p0); pv[1] = (short)f2bf(p1);
            pv[2] = (short)f2bf(p2); pv[3] = (short)f2bf(p3);
            pf[kt] = pv;
        }
        lsum += __shfl_xor(lsum, 16);
        lsum += __shfl_xor(lsum, 32);
        f32x4 oacc = {0.f, 0.f, 0.f, 0.f};
#pragma unroll
        for (int kt = 0; kt < 16; ++kt) {
            bhalf4 vf = *(const bhalf4*)
                &Vbf[(((bh << 4) + lm) << 12) + key0 + (kt << 4) + (lg << 2)];
            oacc = __builtin_amdgcn_mfma_f32_16x16x16bf16_1k(pf[kt], vf, oacc, 0, 0, 0);
        }
        const int pb = ((((buf << 5) + bh) << 4) | ((sp << 1) + kh)) * 64;
        if (lg == 0) {
            pm[pb + qt*16 + lm] = m * 0.25f;
            pl[pb + qt*16 + lm] = lsum;
        }
#pragma unroll
        for (int reg = 0; reg < 4; ++reg)
            po[(pb + qt*16 + (lg << 2) + reg) * 16 + lm] = oacc[reg];
    }
}

// ---------------------------------------------------------------------------
// Epilogue 1: Va = Wv0@anchor_feats, Kn = head-normalize(Wk1@anchor_feats)
// ---------------------------------------------------------------------------
__global__ __launch_bounds__(128) void epi1(
    const float* __restrict__ feats, const float* __restrict__ Wv0,
    const float* __restrict__ Wk1, const int* __restrict__ rings,
    float* __restrict__ Va, float* __restrict__ Kn)
{
    int b = blockIdx.x;
    int i = threadIdx.x;
    int anchor = rings[0];
    __shared__ float la[128];
    __shared__ float kk2[128];
    la[i] = feats[((b * Cn + i) << 12) + anchor];
    __syncthreads();
    float va = 0.f, k1 = 0.f;
    for (int c = 0; c < 128; ++c) {
        va += Wv0[i * 128 + c] * la[c];
        k1 += Wk1[i * 128 + c] * la[c];
    }
    Va[b * 128 + i] = va;
    kk2[i] = k1 * k1;
    __syncthreads();
    float ss = 0.f;
    int hb = i & ~15;
    for (int d = 0; d < 16; ++d) ss += kk2[hb + d];
    Kn[b * 128 + i] = k1 * rsqrtf(ss + 1e-8f);
}

// ---------------------------------------------------------------------------
// Epilogue 2: reg-tiled. Block = 32 cols, 256 thr; W^T staged in LDS once.
// ---------------------------------------------------------------------------
__global__ __launch_bounds__(256) void epi2(
    const float* __restrict__ x, const float* __restrict__ Wq1,
    const float* __restrict__ Va, const float* __restrict__ Kn,
    float* __restrict__ scores)
{
    __shared__ float Wt[128 * 132];
    __shared__ float lxT[128 * 36];
    const int bid = blockIdx.x, t = threadIdx.x;
    const int b = bid >> 7, col0 = (bid & 127) << 5;
    for (int idx = t; idx < 128 * 128; idx += 256) {
        int o = idx >> 7, c = idx & 127;
        Wt[c*132 + o] = Wq1[idx];
    }
    for (int idx = t; idx < 128 * 32; idx += 256) {
        int c = idx >> 5, col = idx & 31;
        lxT[c*36 + col] = x[(((b << 7) + c) << 12) + col0 + col] + Va[(b << 7) + c];
    }
    __syncthreads();
    const int og = t & 31, colg = t >> 5;
    const int o0 = og << 2, cl0 = colg << 2;
    float acc[4][4];
#pragma unroll
    for (int i = 0; i < 4; ++i)
#pragma unroll
        for (int j = 0; j < 4; ++j) acc[i][j] = 0.f;
    for (int c = 0; c < 128; ++c) {
        f32x4 wv = *(const f32x4*)&Wt[c*132 + o0];
        f32x4 xv = *(const f32x4*)&lxT[c*36 + cl0];
#pragma unroll
        for (int i = 0; i < 4; ++i)
#pragma unroll
            for (int j = 0; j < 4; ++j) acc[i][j] += wv[i] * xv[j];
    }
    float kn4[4];
#pragma unroll
    for (int i = 0; i < 4; ++i) kn4[i] = Kn[(b << 7) + o0 + i];
    float res[4];
#pragma unroll
    for (int j = 0; j < 4; ++j) {
        float ss = acc[0][j]*acc[0][j] + acc[1][j]*acc[1][j]
                 + acc[2][j]*acc[2][j] + acc[3][j]*acc[3][j];
        ss += __shfl_xor(ss, 1);
        ss += __shfl_xor(ss, 2);
        float rs = rsqrtf(ss + 1e-8f);
        float mp = (acc[0][j]*kn4[0] + acc[1][j]*kn4[1]
                  + acc[2][j]*kn4[2] + acc[3][j]*kn4[3]) * rs;
#pragma unroll
        for (int msk = 1; msk <= 16; msk <<= 1) mp += __shfl_xor(mp, msk);
        res[j] = 0.5f + mp * (1.0f / 16.0f);
    }
    if (og == 0) {
#pragma unroll
        for (int j = 0; j < 4; ++j)
            scores[(b << 12) + col0 + cl0 + j] = res[j];
    }
}

// ---------------------------------------------------------------------------
// Launcher: 1 init + 127 fused + 1 tail + 2 epilogues = 131 launches.
// ---------------------------------------------------------------------------
extern "C" void kernel_launch(void* const* d_in, const int* in_sizes, int n_in,
                              void* d_out, int out_size, void* d_ws, size_t ws_size,
                              hipStream_t stream) {
    const float* x   = (const float*)d_in[0];
    const float* Wq0 = (const float*)d_in[1];
    const float* Wk0 = (const float*)d_in[2];
    const float* Wv0 = (const float*)d_in[3];
    const float* Wq1 = (const float*)d_in[4];
    const float* Wk1 = (const float*)d_in[5];
    const int*   rings = (const int*)d_in[6];
    const int*   rsz   = (const int*)d_in[7];

    float* feats  = (float*)d_out;                 // (B,C,F)
    float* scores = feats + Bn * Cn * Fn;          // (B,F)

    float*  ws   = (float*)d_ws;
    ushort* Q0bf = (ushort*)ws;
    ushort* Kbf  = (ushort*)(ws + OFF_K);
    ushort* Vbf  = (ushort*)(ws + OFF_V);
    float*  pm   = ws + OFF_PM;
    float*  pl   = ws + OFF_PL;
    float*  po   = ws + OFF_PO;
    float*  Va   = ws + OFF_VA;
    float*  Kn   = ws + OFF_KN;

    initQKV<<<256, 512, 0, stream>>>(x, Wq0, Wk0, Wv0, Q0bf, Kbf, Vbf);

    for (int r = 0; r < NRINGS; ++r) {
        fusedRing<false><<<256, 512, 0, stream>>>(
            x, Wk0, Wv0, rings, rsz, Q0bf, Kbf, Vbf, pm, pl, po, feats, r);
    }
    fusedRing<true><<<256, 512, 0, stream>>>(
        x, Wk0, Wv0, rings, rsz, Q0bf, Kbf, Vbf, pm, pl, po, feats, NRINGS);

    epi1<<<Bn, 128, 0, stream>>>(feats, Wv0, Wk1, rings, Va, Kn);
    epi2<<<512, 256, 0, stream>>>(x, Wq1, Va, Kn, scores);
}

// Round 7
// 4817.470 us; speedup vs baseline: 1.1888x; 1.1888x over previous
//
#include <hip/hip_runtime.h>
#include <hip/hip_bf16.h>

// (B,C,H,G) = (4,128,8,64); F=4096, DH=16, 127 rings.
#define Bn 4
#define Cn 128
#define Fn 4096
#define NRINGS 127
#define NWG 64

typedef short bhalf4 __attribute__((ext_vector_type(4)));
typedef float f32x4  __attribute__((ext_vector_type(4)));

// workspace offsets (float-slot units)
#define OFF_K    1048576
#define OFF_V    2097152
#define OFF_PM   3145728   // 65536 (fallback needs 16-slice layout)
#define OFF_PL   3211264   // 65536
#define OFF_PO   3276800   // 1048576
#define OFF_OUTC 4325376   // 32768
#define OFF_VA   4358144
#define OFF_KN   4358656
#define OFF_BAR  4359168

__device__ __forceinline__ ushort f2bf(float f) {
    __hip_bfloat16 h = __float2bfloat16(f);
    return *reinterpret_cast<ushort*>(&h);
}

// ---------------------------------------------------------------------------
// init: Q0bf/Kbf rows [b][h][col][16] bf16; Vbf transposed [b][h][d][col] bf16.
// Also zeroes the device barrier counter (must happen every launch).
// ---------------------------------------------------------------------------
__global__ __launch_bounds__(512, 2) void initQKV(
    const float* __restrict__ x, const float* __restrict__ Wq0,
    const float* __restrict__ Wk0, const float* __restrict__ Wv0,
    ushort* __restrict__ Q0bf, ushort* __restrict__ Kbf, ushort* __restrict__ Vbf,
    int* __restrict__ bar)
{
    __shared__ float xs[Cn * 64];
    __shared__ float Wls[3 * 128 * 33];
    const int wg = blockIdx.x, t = threadIdx.x;
    if (wg == 0 && t == 0) bar[0] = 0;
    const int b = wg >> 6, n0 = (wg & 63) << 6;
    for (int idx = t; idx < Cn * 64; idx += 512) {
        int c = idx >> 6, j = idx & 63;
        xs[idx] = x[(((b << 7) + c) << 12) + n0 + j];
    }
    const int o = t & 127, j0 = (t >> 7) << 4;
    float aq[16], ak[16], av[16];
#pragma unroll
    for (int k = 0; k < 16; ++k) { aq[k] = 0.f; ak[k] = 0.f; av[k] = 0.f; }
    for (int cc = 0; cc < 128; cc += 32) {
        __syncthreads();
        for (int idx = t; idx < 128 * 32; idx += 512) {
            int oo = idx >> 5, jj = idx & 31;
            Wls[oo * 33 + jj]                = Wq0[(oo << 7) + cc + jj];
            Wls[128 * 33 + oo * 33 + jj]     = Wk0[(oo << 7) + cc + jj];
            Wls[2 * 128 * 33 + oo * 33 + jj] = Wv0[(oo << 7) + cc + jj];
        }
        __syncthreads();
        for (int c2 = 0; c2 < 32; ++c2) {
            float wq = Wls[o * 33 + c2];
            float wk = Wls[128 * 33 + o * 33 + c2];
            float wv = Wls[2 * 128 * 33 + o * 33 + c2];
            const float* xr = &xs[((cc + c2) << 6) + j0];
#pragma unroll
            for (int k = 0; k < 16; ++k) {
                float xv = xr[k];
                aq[k] += wq * xv; ak[k] += wk * xv; av[k] += wv * xv;
            }
        }
    }
    const int h = o >> 4, d = o & 15;
    const int bh = (b << 3) + h;
#pragma unroll
    for (int k = 0; k < 16; ++k) {
        int col = n0 + j0 + k;
        int qi = ((bh << 12) + col) * 16 + d;
        Q0bf[qi] = f2bf(aq[k]);
        Kbf[qi]  = f2bf(ak[k]);
    }
    uint vv[8];
#pragma unroll
    for (int k2 = 0; k2 < 8; ++k2)
        vv[k2] = (uint)f2bf(av[2*k2]) | ((uint)f2bf(av[2*k2+1]) << 16);
    uint4* dst = (uint4*)&Vbf[(((bh << 4) + d) << 12) + n0 + j0];
    dst[0] = make_uint4(vv[0], vv[1], vv[2], vv[3]);
    dst[1] = make_uint4(vv[4], vv[5], vv[6], vv[7]);
}

// ---------------------------------------------------------------------------
// Device-wide barrier: monotonic counter, agent-scope atomics, relaxed spin.
// ---------------------------------------------------------------------------
__device__ __forceinline__ void gbar(int* bar, int target) {
    __syncthreads();
    if (threadIdx.x == 0) {
        __threadfence();   // release: flush partials/outc to coherent point
        __hip_atomic_fetch_add(bar, 1, __ATOMIC_RELEASE, __HIP_MEMORY_SCOPE_AGENT);
        while (__hip_atomic_load(bar, __ATOMIC_RELAXED, __HIP_MEMORY_SCOPE_AGENT) < target)
            __builtin_amdgcn_s_sleep(2);
        __threadfence();   // acquire: invalidate stale L1/L2 lines
    }
    __syncthreads();
}

// ---------------------------------------------------------------------------
// flash for one ring over this WG's LDS-resident K/V (2048 keys).
// 8 waves: qt=w&3 (16 queries), kq=w>>2 (1024 keys). Two-pass (max, exp+PV).
// ---------------------------------------------------------------------------
__device__ __forceinline__ void flashStep(
    int n, int buf, int bh, int kv, int t,
    const ushort* qs, const ushort* Kls, const ushort* Vls,
    float* __restrict__ pm, float* __restrict__ pl, float* __restrict__ po)
{
    const int w = t >> 6, lane = t & 63;
    const int qt = w & 3, kq = w >> 2;
    if (qt * 16 >= n) return;
    const int lm = lane & 15, lg = lane >> 4;
    bhalf4 qf = *(const bhalf4*)&qs[(qt * 16 + lm) * 20 + (lg << 2)];
    const int kbase = kq << 10;

    float m = -3e38f;
#pragma unroll 4
    for (int kt = 0; kt < 64; ++kt) {
        bhalf4 kf = *(const bhalf4*)&Kls[(kbase + (kt << 4) + lm) * 20 + (lg << 2)];
        f32x4 z = {0.f, 0.f, 0.f, 0.f};
        f32x4 s = __builtin_amdgcn_mfma_f32_16x16x16bf16_1k(kf, qf, z, 0, 0, 0);
        m = fmaxf(m, fmaxf(fmaxf(s[0], s[1]), fmaxf(s[2], s[3])));
    }
    m = fmaxf(m, __shfl_xor(m, 16));
    m = fmaxf(m, __shfl_xor(m, 32));

    float lsum = 0.f;
    f32x4 oacc = {0.f, 0.f, 0.f, 0.f};
#pragma unroll 4
    for (int kt = 0; kt < 64; ++kt) {
        bhalf4 kf = *(const bhalf4*)&Kls[(kbase + (kt << 4) + lm) * 20 + (lg << 2)];
        f32x4 z = {0.f, 0.f, 0.f, 0.f};
        f32x4 s = __builtin_amdgcn_mfma_f32_16x16x16bf16_1k(kf, qf, z, 0, 0, 0);
        float p0 = __expf((s[0] - m) * 0.25f);
        float p1 = __expf((s[1] - m) * 0.25f);
        float p2 = __expf((s[2] - m) * 0.25f);
        float p3 = __expf((s[3] - m) * 0.25f);
        lsum += (p0 + p1) + (p2 + p3);
        bhalf4 pv;
        pv[0] = (short)f2bf(p0); pv[1] = (short)f2bf(p1);
        pv[2] = (short)f2bf(p2); pv[3] = (short)f2bf(p3);
        bhalf4 vf = *(const bhalf4*)&Vls[lm * 2056 + kbase + (kt << 4) + (lg << 2)];
        oacc = __builtin_amdgcn_mfma_f32_16x16x16bf16_1k(pv, vf, oacc, 0, 0, 0);
    }
    lsum += __shfl_xor(lsum, 16);
    lsum += __shfl_xor(lsum, 32);

    const int sl = (kv << 1) + kq;
    const int pb = ((((buf << 5) + bh) << 2) + sl) * 64;
    if (lg == 0) {
        pm[pb + qt * 16 + lm] = m * 0.25f;
        pl[pb + qt * 16 + lm] = lsum;
    }
#pragma unroll
    for (int reg = 0; reg < 4; ++reg)
        po[(pb + qt * 16 + (lg << 2) + reg) * 16 + lm] = oacc[reg];
}

// ---------------------------------------------------------------------------
// P1: merge 4 partial slices for this head's 16 channels; write outc + feats.
// threads: jj=t>>4 (32 ring-cols per kv-half), dd=t&15.
// ---------------------------------------------------------------------------
__device__ __forceinline__ void combineP1(
    int np, int bufp, int b, int h, int kv, int t,
    const int* colsC, const float* __restrict__ x,
    const float* __restrict__ pm, const float* __restrict__ pl,
    const float* __restrict__ po, float* __restrict__ outcG,
    float* __restrict__ feats)
{
    int jj = t >> 4, dd = t & 15;
    int jq = (kv << 5) + jj;
    if (jq >= np) return;
    int bh = (b << 3) + h;
    int col = colsC[jq];
    int p0 = ((((bufp << 5) + bh) << 2) << 6) + jq;
    float mstar = -3e38f;
#pragma unroll
    for (int sl = 0; sl < 4; ++sl) mstar = fmaxf(mstar, pm[p0 + (sl << 6)]);
    float lstar = 0.f, osum = 0.f;
#pragma unroll
    for (int sl = 0; sl < 4; ++sl) {
        int pi = p0 + (sl << 6);
        float e = __expf(pm[pi] - mstar);
        lstar += pl[pi] * e;
        osum  += po[(pi << 4) + dd] * e;
    }
    float outv = osum / lstar + x[(((b << 7) + (h << 4) + dd) << 12) + col];
    outcG[(((b << 6) + jq) << 7) + (h << 4) + dd] = outv;
    feats[(((b << 7) + (h << 4) + dd) << 12) + col] = outv;
}

// ---------------------------------------------------------------------------
// P2: for owned ring cols, GEMV own head's 16 K-rows + 16 V-rows from outc,
// patch LDS K/V. threads: slot=t>>6 (8 cols/batch), rr=(t>>1)&31, half=t&1.
// ---------------------------------------------------------------------------
__device__ __forceinline__ void patchP2(
    int np, int b, int h, int kv, int t,
    const int* colsC, int* ownIdx, int* ownCnt,
    const float* __restrict__ Wk0, const float* __restrict__ Wv0,
    const float* __restrict__ outcG, ushort* Kls, ushort* Vls)
{
    const int keyG0 = kv << 11;
    if (t < np) {
        int cq = colsC[t];
        if (cq >= keyG0 && cq < keyG0 + 2048)
            ownIdx[atomicAdd(ownCnt, 1)] = t;
    }
    __syncthreads();
    const int cnt = *ownCnt;
    const int slot = t >> 6, rr = (t >> 1) & 31, half = t & 1;
    const int dd = rr & 15;
    for (int base = 0; base < cnt; base += 8) {
        int ow = base + slot;
        if (ow < cnt) {
            int jq = ownIdx[ow];
            int col = colsC[jq];
            const float* W = (rr < 16) ? Wk0 : Wv0;
            int row = (h << 4) + dd;
            const f32x4* W4  = (const f32x4*)&W[(row << 7) + (half << 6)];
            const f32x4* oc4 = (const f32x4*)&outcG[(((b << 6) + jq) << 7) + (half << 6)];
            float acc = 0.f;
#pragma unroll
            for (int c4 = 0; c4 < 16; ++c4) {
                f32x4 wv = W4[c4], xv = oc4[c4];
                acc += wv[0]*xv[0] + wv[1]*xv[1] + wv[2]*xv[2] + wv[3]*xv[3];
            }
            acc += __shfl_xor(acc, 1);
            if (half == 0) {
                ushort bfv = f2bf(acc);
                int colL = col - keyG0;
                if (rr < 16) Kls[colL * 20 + dd] = bfv;
                else         Vls[dd * 2056 + colL] = bfv;
            }
        }
    }
}

// ---------------------------------------------------------------------------
// Persistent kernel: 64 WGs (b,h,kv) x 512 thr, K/V LDS-resident, 2 light
// barriers per ring. Partials double-buffered by ring parity.
// ---------------------------------------------------------------------------
__global__ __launch_bounds__(512, 1) void ringPersist(
    const float* __restrict__ x, const float* __restrict__ Wk0,
    const float* __restrict__ Wv0, const int* __restrict__ rings,
    const int* __restrict__ rsz, const ushort* __restrict__ Q0bf,
    const ushort* __restrict__ Kbf, const ushort* __restrict__ Vbf,
    float* __restrict__ pm, float* __restrict__ pl, float* __restrict__ po,
    float* __restrict__ outcG, float* __restrict__ feats, int* bar)
{
    __shared__ ushort Kls[2048 * 20];   // 80 KB, stride 40B (2-way banks)
    __shared__ ushort Vls[16 * 2056];   // 64.25 KB, V^T rows stride 4112B
    __shared__ ushort qs[64 * 20];
    __shared__ int colsC[64], colsF[64], ownIdx[64];
    __shared__ int ownCnt;

    const int wg = blockIdx.x, t = threadIdx.x;
    const int b = wg >> 4, h = (wg >> 1) & 7, kv = wg & 1;
    const int bh = (b << 3) + h;
    const int keyG0 = kv << 11;
    int bstep = 0;

    // ---- one-time stage: K rows + V^T rows into LDS ----
    for (int idx = t; idx < 2048 * 4; idx += 512) {
        int key = idx >> 2, qtr = idx & 3;
        *(uint2*)&Kls[key * 20 + (qtr << 2)] =
            *(const uint2*)&Kbf[(((bh << 12) + keyG0 + key) << 4) + (qtr << 2)];
    }
    for (int idx = t; idx < 16 * 256; idx += 512) {
        int d = idx >> 8, c8 = idx & 255;
        *(uint4*)&Vls[d * 2056 + (c8 << 3)] =
            *(const uint4*)&Vbf[(((bh << 4) + d) << 12) + keyG0 + (c8 << 3)];
    }

    // ---- ring 0 flash ----
    {
        const int n0r = rsz[0];
        if (t < 64) colsF[t] = (t < n0r) ? rings[t] : 0;
        __syncthreads();
        if (t < 256) {
            int j = t >> 2, qtr = t & 3;
            int cq = colsF[j];
            *(uint2*)&qs[j * 20 + (qtr << 2)] =
                *(const uint2*)&Q0bf[(((bh << 12) + cq) << 4) + (qtr << 2)];
        }
        __syncthreads();
        flashStep(n0r, 0, bh, kv, t, qs, Kls, Vls, pm, pl, po);
    }

    // ---- rings 1..126 ----
    for (int r = 1; r < NRINGS; ++r) {
        const int np = rsz[r - 1], n = rsz[r];
        const int bufp = (r - 1) & 1;
        gbar(bar, NWG * (++bstep));          // partials(r-1) visible
        if (t < 64) colsC[t] = (t < np) ? rings[(r - 1) * 64 + t] : -1;
        else if (t < 128) colsF[t - 64] = (t - 64 < n) ? rings[r * 64 + t - 64] : 0;
        if (t == 0) ownCnt = 0;
        __syncthreads();
        combineP1(np, bufp, b, h, kv, t, colsC, x, pm, pl, po, outcG, feats);
        gbar(bar, NWG * (++bstep));          // outc visible
        patchP2(np, b, h, kv, t, colsC, ownIdx, &ownCnt, Wk0, Wv0, outcG, Kls, Vls);
        __syncthreads();
        if (t < 256) {                        // stage qs for ring r
            int j = t >> 2, qtr = t & 3;
            int cq = colsF[j];
            *(uint2*)&qs[j * 20 + (qtr << 2)] =
                *(const uint2*)&Q0bf[(((bh << 12) + cq) << 4) + (qtr << 2)];
        }
        __syncthreads();
        flashStep(n, r & 1, bh, kv, t, qs, Kls, Vls, pm, pl, po);
    }

    // ---- final combine for ring 126 (feats only) ----
    {
        gbar(bar, NWG * (++bstep));
        const int np = rsz[NRINGS - 1];
        if (t < 64) colsC[t] = (t < np) ? rings[(NRINGS - 1) * 64 + t] : -1;
        __syncthreads();
        combineP1(np, (NRINGS - 1) & 1, b, h, kv, t, colsC, x, pm, pl, po,
                  outcG, feats);
    }
}

// ---------------------------------------------------------------------------
// FALLBACK path: R5's proven per-ring kernel (LDS-staged K/V), 1781 us.
// ---------------------------------------------------------------------------
template<bool TAIL>
__global__ __launch_bounds__(512, 2) void fusedRingFB(
    const float* __restrict__ x, const float* __restrict__ Wk0,
    const float* __restrict__ Wv0, const int* __restrict__ rings,
    const int* __restrict__ rsz, const ushort* __restrict__ Q0bf,
    ushort* __restrict__ Kbf, ushort* __restrict__ Vbf,
    float* __restrict__ pm, float* __restrict__ pl, float* __restrict__ po,
    float* __restrict__ feats, int r)
{
    __shared__ ushort Kls[512 * 24];
    __shared__ ushort Vls[16 * 520];
    __shared__ ushort Qls[64 * 24];
    __shared__ float  outc[4 * 128];
    __shared__ int colsC[64], colsF[64];
    __shared__ int ownIdx[64];
    __shared__ int ownCnt;

    const int t = threadIdx.x, wgid = blockIdx.x;
    const int b = wgid >> 6, h = (wgid >> 3) & 7, sp = wgid & 7;
    const int bh = (b << 3) + h;
    const int n  = TAIL ? 0 : rsz[r];
    const int np = (r > 0) ? rsz[r - 1] : 0;
    const int keybase = sp << 9;

    if (t < 64) colsC[t] = (r > 0 && t < np) ? rings[(r-1)*64 + t] : -1;
    else if (t < 128) { int q = t - 64; colsF[q] = (!TAIL && q < n) ? rings[r*64 + q] : 0; }
    if (t == 0) ownCnt = 0;
    __syncthreads();

    if (!TAIL) {
        {
            const uint4* src = (const uint4*)(Kbf + ((bh << 12) + keybase + t) * 16);
            uint4 a0 = src[0], a1 = src[1];
            *(uint4*)&Kls[t*24]     = a0;
            *(uint4*)&Kls[t*24 + 8] = a1;
        }
        {
            int d = t >> 5, c32 = t & 31;
            const uint4* src = (const uint4*)(Vbf + (((bh << 4) + d) << 12) + keybase + (c32 << 4));
            uint4 a0 = src[0], a1 = src[1];
            *(uint4*)&Vls[d*520 + (c32 << 4)]     = a0;
            *(uint4*)&Vls[d*520 + (c32 << 4) + 8] = a1;
        }
        if (t < 128) {
            int q = t >> 1, half = t & 1;
            int cq = colsF[q];
            uint4 qv = *(const uint4*)(Q0bf + ((bh << 12) + cq) * 16 + half * 8);
            *(uint4*)&Qls[q*24 + half*8] = qv;
        }
    }
    __syncthreads();

    if (r > 0) {
        const int bufp = (r - 1) & 1;
        if (t < np) {
            int cq = colsC[t];
            if (cq >= keybase && cq < keybase + 512) {
                int slot = atomicAdd(&ownCnt, 1);
                ownIdx[slot] = t;
            }
        }
        __syncthreads();
        const int cnt = ownCnt;
        for (int base = 0; base < cnt; base += 4) {
            {
                int slot = t >> 7, c = t & 127;
                int ow = base + slot;
                if (ow < cnt) {
                    int j = ownIdx[ow];
                    int col = colsC[j];
                    int hh = c >> 4, dd = c & 15;
                    int p0 = ((bufp << 5) + (b << 3) + hh) * 1024 + j;
                    float mstar = -1e30f;
#pragma unroll
                    for (int s2 = 0; s2 < 16; ++s2)
                        mstar = fmaxf(mstar, pm[p0 + (s2 << 6)]);
                    float lstar = 0.f, osum = 0.f;
#pragma unroll
                    for (int s2 = 0; s2 < 16; ++s2) {
                        int pi = p0 + (s2 << 6);
                        float e = __expf(pm[pi] - mstar);
                        lstar += pl[pi] * e;
                        osum  += po[(pi << 4) + dd] * e;
                    }
                    float outv = osum / lstar + x[(((b << 7) + c) << 12) + col];
                    outc[(slot << 7) + c] = outv;
                    if (h == 0) feats[(((b << 7) + c) << 12) + col] = outv;
                }
            }
            __syncthreads();
            if (!TAIL && t < 128) {
                int slot = t >> 5;
                int ow = base + slot;
                if (ow < cnt) {
                    int task = t & 31;
                    int isV = task >> 4, dd = task & 15;
                    int col = colsC[ownIdx[ow]];
                    const float* W = isV ? Wv0 : Wk0;
                    const float* oc = &outc[slot << 7];
                    int row = (h << 4) + dd;
                    float acc = 0.f;
                    for (int c2 = 0; c2 < Cn; ++c2)
                        acc += W[(row << 7) + c2] * oc[c2];
                    ushort bfv = f2bf(acc);
                    if (isV) {
                        Vbf[(((bh << 4) + dd) << 12) + col] = bfv;
                        Vls[dd*520 + (col - keybase)] = bfv;
                    } else {
                        Kbf[((bh << 12) + col) * 16 + dd] = bfv;
                        Kls[(col - keybase)*24 + dd] = bfv;
                    }
                }
            }
            __syncthreads();
        }
    }
    if (TAIL) return;

    const int w = t >> 6, lane = t & 63;
    const int qt = w & 3, kh = w >> 2;
    const int buf = r & 1;
    if (qt * 16 < n) {
        const int lm = lane & 15, lg = lane >> 4;
        bhalf4 qf = *(const bhalf4*)&Qls[(qt*16 + lm)*24 + (lg << 2)];
        const int key0 = kh << 8;
        f32x4 sc[16];
#pragma unroll
        for (int kt = 0; kt < 16; ++kt) {
            bhalf4 kf = *(const bhalf4*)&Kls[(key0 + (kt << 4) + lm)*24 + (lg << 2)];
            f32x4 z = {0.f, 0.f, 0.f, 0.f};
            sc[kt] = __builtin_amdgcn_mfma_f32_16x16x16bf16_1k(kf, qf, z, 0, 0, 0);
        }
        float m = -1e30f;
#pragma unroll
        for (int kt = 0; kt < 16; ++kt)
            m = fmaxf(m, fmaxf(fmaxf(sc[kt][0], sc[kt][1]), fmaxf(sc[kt][2], sc[kt][3])));
        m = fmaxf(m, __shfl_xor(m, 16));
        m = fmaxf(m, __shfl_xor(m, 32));
        float lsum = 0.f;
        bhalf4 pf[16];
#pragma unroll
        for (int kt = 0; kt < 16; ++kt) {
            float p0 = __expf((sc[kt][0] - m) * 0.25f);
            float p1 = __expf((sc[kt][1] - m) * 0.25f);
            float p2 = __expf((sc[kt][2] - m) * 0.25f);
            float p3 = __expf((sc[kt][3] - m) * 0.25f);
            lsum += (p0 + p1) + (p2 + p3);
            bhalf4 pv;
            pv[0] = (short)f2bf(p0); pv[1] = (short)f2bf(p1);
            pv[2] = (short)f2bf(p2); pv[3] = (short)f2bf(p3);
            pf[kt] = pv;
        }
        lsum += __shfl_xor(lsum, 16);
        lsum += __shfl_xor(lsum, 32);
        f32x4 oacc = {0.f, 0.f, 0.f, 0.f};
#pragma unroll
        for (int kt = 0; kt < 16; ++kt) {
            bhalf4 vf = *(const bhalf4*)&Vls[lm*520 + key0 + (kt << 4) + (lg << 2)];
            oacc = __builtin_amdgcn_mfma_f32_16x16x16bf16_1k(pf[kt], vf, oacc, 0, 0, 0);
        }
        const int pb = ((((buf << 5) + bh) << 4) | ((sp << 1) + kh)) * 64;
        if (lg == 0) {
            pm[pb + qt*16 + lm] = m * 0.25f;
            pl[pb + qt*16 + lm] = lsum;
        }
#pragma unroll
        for (int reg = 0; reg < 4; ++reg)
            po[(pb + qt*16 + (lg << 2) + reg) * 16 + lm] = oacc[reg];
    }
}

// ---------------------------------------------------------------------------
// Epilogues
// ---------------------------------------------------------------------------
__global__ __launch_bounds__(128) void epi1(
    const float* __restrict__ feats, const float* __restrict__ Wv0,
    const float* __restrict__ Wk1, const int* __restrict__ rings,
    float* __restrict__ Va, float* __restrict__ Kn)
{
    int b = blockIdx.x;
    int i = threadIdx.x;
    int anchor = rings[0];
    __shared__ float la[128];
    __shared__ float kk2[128];
    la[i] = feats[((b * Cn + i) << 12) + anchor];
    __syncthreads();
    float va = 0.f, k1 = 0.f;
    for (int c = 0; c < 128; ++c) {
        va += Wv0[i * 128 + c] * la[c];
        k1 += Wk1[i * 128 + c] * la[c];
    }
    Va[b * 128 + i] = va;
    kk2[i] = k1 * k1;
    __syncthreads();
    float ss = 0.f;
    int hb = i & ~15;
    for (int d = 0; d < 16; ++d) ss += kk2[hb + d];
    Kn[b * 128 + i] = k1 * rsqrtf(ss + 1e-8f);
}

__global__ __launch_bounds__(256) void epi2(
    const float* __restrict__ x, const float* __restrict__ Wq1,
    const float* __restrict__ Va, const float* __restrict__ Kn,
    float* __restrict__ scores)
{
    __shared__ float Wt[128 * 132];
    __shared__ float lxT[128 * 36];
    const int bid = blockIdx.x, t = threadIdx.x;
    const int b = bid >> 7, col0 = (bid & 127) << 5;
    for (int idx = t; idx < 128 * 128; idx += 256) {
        int o = idx >> 7, c = idx & 127;
        Wt[c*132 + o] = Wq1[idx];
    }
    for (int idx = t; idx < 128 * 32; idx += 256) {
        int c = idx >> 5, col = idx & 31;
        lxT[c*36 + col] = x[(((b << 7) + c) << 12) + col0 + col] + Va[(b << 7) + c];
    }
    __syncthreads();
    const int og = t & 31, colg = t >> 5;
    const int o0 = og << 2, cl0 = colg << 2;
    float acc[4][4];
#pragma unroll
    for (int i = 0; i < 4; ++i)
#pragma unroll
        for (int j = 0; j < 4; ++j) acc[i][j] = 0.f;
    for (int c = 0; c < 128; ++c) {
        f32x4 wv = *(const f32x4*)&Wt[c*132 + o0];
        f32x4 xv = *(const f32x4*)&lxT[c*36 + cl0];
#pragma unroll
        for (int i = 0; i < 4; ++i)
#pragma unroll
            for (int j = 0; j < 4; ++j) acc[i][j] += wv[i] * xv[j];
    }
    float kn4[4];
#pragma unroll
    for (int i = 0; i < 4; ++i) kn4[i] = Kn[(b << 7) + o0 + i];
    float res[4];
#pragma unroll
    for (int j = 0; j < 4; ++j) {
        float ss = acc[0][j]*acc[0][j] + acc[1][j]*acc[1][j]
                 + acc[2][j]*acc[2][j] + acc[3][j]*acc[3][j];
        ss += __shfl_xor(ss, 1);
        ss += __shfl_xor(ss, 2);
        float rs = rsqrtf(ss + 1e-8f);
        float mp = (acc[0][j]*kn4[0] + acc[1][j]*kn4[1]
                  + acc[2][j]*kn4[2] + acc[3][j]*kn4[3]) * rs;
#pragma unroll
        for (int msk = 1; msk <= 16; msk <<= 1) mp += __shfl_xor(mp, msk);
        res[j] = 0.5f + mp * (1.0f / 16.0f);
    }
    if (og == 0) {
#pragma unroll
        for (int j = 0; j < 4; ++j)
            scores[(b << 12) + col0 + cl0 + j] = res[j];
    }
}

// ---------------------------------------------------------------------------
// Launcher
// ---------------------------------------------------------------------------
extern "C" void kernel_launch(void* const* d_in, const int* in_sizes, int n_in,
                              void* d_out, int out_size, void* d_ws, size_t ws_size,
                              hipStream_t stream) {
    const float* x   = (const float*)d_in[0];
    const float* Wq0 = (const float*)d_in[1];
    const float* Wk0 = (const float*)d_in[2];
    const float* Wv0 = (const float*)d_in[3];
    const float* Wq1 = (const float*)d_in[4];
    const float* Wk1 = (const float*)d_in[5];
    const int*   rings = (const int*)d_in[6];
    const int*   rsz   = (const int*)d_in[7];

    float* feats  = (float*)d_out;                 // (B,C,F)
    float* scores = feats + Bn * Cn * Fn;          // (B,F)

    float*  ws    = (float*)d_ws;
    ushort* Q0bf  = (ushort*)ws;
    ushort* Kbf   = (ushort*)(ws + OFF_K);
    ushort* Vbf   = (ushort*)(ws + OFF_V);
    float*  pm    = ws + OFF_PM;
    float*  pl    = ws + OFF_PL;
    float*  po    = ws + OFF_PO;
    float*  outcG = ws + OFF_OUTC;
    float*  Va    = ws + OFF_VA;
    float*  Kn    = ws + OFF_KN;
    int*    bar   = (int*)(ws + OFF_BAR);

    initQKV<<<256, 512, 0, stream>>>(x, Wq0, Wk0, Wv0, Q0bf, Kbf, Vbf, bar);

    void* args[] = { (void*)&x, (void*)&Wk0, (void*)&Wv0, (void*)&rings,
                     (void*)&rsz, (void*)&Q0bf, (void*)&Kbf, (void*)&Vbf,
                     (void*)&pm, (void*)&pl, (void*)&po, (void*)&outcG,
                     (void*)&feats, (void*)&bar };
    hipError_t le = hipLaunchCooperativeKernel((void*)ringPersist, dim3(NWG),
                                               dim3(512), args, 0, stream);
    if (le != hipSuccess) {
        for (int r = 0; r < NRINGS; ++r) {
            fusedRingFB<false><<<256, 512, 0, stream>>>(
                x, Wk0, Wv0, rings, rsz, Q0bf, Kbf, Vbf, pm, pl, po, feats, r);
        }
        fusedRingFB<true><<<256, 512, 0, stream>>>(
            x, Wk0, Wv0, rings, rsz, Q0bf, Kbf, Vbf, pm, pl, po, feats, NRINGS);
    }

    epi1<<<Bn, 128, 0, stream>>>(feats, Wv0, Wk1, rings, Va, Kn);
    epi2<<<512, 256, 0, stream>>>(x, Wq1, Va, Kn, scores);
}

// Round 8
// 3311.389 us; speedup vs baseline: 1.7295x; 1.4548x over previous
//
#include <hip/hip_runtime.h>
#include <hip/hip_bf16.h>

// (B,C,H,G) = (4,128,8,64); F=4096, DH=16, 127 rings.
#define Bn 4
#define Cn 128
#define Fn 4096
#define NRINGS 127

typedef short bhalf4 __attribute__((ext_vector_type(4)));
typedef float f32x4  __attribute__((ext_vector_type(4)));

// workspace offsets (float-slot units)
#define OFF_Q0   0          // Q0bf: 32*4096*16 shorts = 1,048,576 fl
#define OFF_KP   1048576    // Kp padded: 32*4096*24 shorts = 1,572,864 fl
#define OFF_VP   2621440    // Vp (V^T): 32*16*4096 shorts = 1,048,576 fl
#define OFF_PM   3670016    // pm2: 2*32*512 = 32,768 fl
#define OFF_PL   3702784    // pl2: 32,768 fl
#define OFF_PO   3735552    // po2: 2*32*64*16*8 = 524,288 fl
#define OFF_VA   4259840
#define OFF_KN   4260352

__device__ __forceinline__ ushort f2bf(float f) {
    __hip_bfloat16 h = __float2bfloat16(f);
    return *reinterpret_cast<ushort*>(&h);
}

// ---------------------------------------------------------------------------
// init: Q0bf rows [bh][col][16]; Kp PADDED rows [bh][key][24] (48B, for clean
// staging + 2-way LDS banks); Vp transposed [bh][d][4096]. bf16.
// ---------------------------------------------------------------------------
__global__ __launch_bounds__(512, 2) void initQKV(
    const float* __restrict__ x, const float* __restrict__ Wq0,
    const float* __restrict__ Wk0, const float* __restrict__ Wv0,
    ushort* __restrict__ Q0bf, ushort* __restrict__ Kp, ushort* __restrict__ Vp)
{
    __shared__ float xs[Cn * 64];
    __shared__ float Wls[3 * 128 * 33];
    const int wg = blockIdx.x, t = threadIdx.x;
    const int b = wg >> 6, n0 = (wg & 63) << 6;
    for (int idx = t; idx < Cn * 64; idx += 512) {
        int c = idx >> 6, j = idx & 63;
        xs[idx] = x[(size_t)(((b << 7) + c)) * 4096 + n0 + j];
    }
    const int o = t & 127, j0 = (t >> 7) << 4;
    float aq[16], ak[16], av[16];
#pragma unroll
    for (int k = 0; k < 16; ++k) { aq[k] = 0.f; ak[k] = 0.f; av[k] = 0.f; }
    for (int cc = 0; cc < 128; cc += 32) {
        __syncthreads();
        for (int idx = t; idx < 128 * 32; idx += 512) {
            int oo = idx >> 5, jj = idx & 31;
            Wls[oo * 33 + jj]                = Wq0[(oo << 7) + cc + jj];
            Wls[128 * 33 + oo * 33 + jj]     = Wk0[(oo << 7) + cc + jj];
            Wls[2 * 128 * 33 + oo * 33 + jj] = Wv0[(oo << 7) + cc + jj];
        }
        __syncthreads();
        for (int c2 = 0; c2 < 32; ++c2) {
            float wq = Wls[o * 33 + c2];
            float wk = Wls[128 * 33 + o * 33 + c2];
            float wv = Wls[2 * 128 * 33 + o * 33 + c2];
            const f32x4* xr4 = (const f32x4*)&xs[((cc + c2) << 6) + j0];
#pragma unroll
            for (int k4 = 0; k4 < 4; ++k4) {
                f32x4 xv = xr4[k4];
#pragma unroll
                for (int e = 0; e < 4; ++e) {
                    int k = (k4 << 2) + e;
                    aq[k] += wq * xv[e]; ak[k] += wk * xv[e]; av[k] += wv * xv[e];
                }
            }
        }
    }
    const int h = o >> 4, d = o & 15;
    const int bh = (b << 3) + h;
#pragma unroll
    for (int k = 0; k < 16; ++k) {
        int col = n0 + j0 + k;
        Q0bf[(size_t)(bh * 4096 + col) * 16 + d] = f2bf(aq[k]);
        Kp  [(size_t)(bh * 4096 + col) * 24 + d] = f2bf(ak[k]);
    }
    uint vv[8];
#pragma unroll
    for (int k2 = 0; k2 < 8; ++k2)
        vv[k2] = (uint)f2bf(av[2*k2]) | ((uint)f2bf(av[2*k2+1]) << 16);
    uint4* dst = (uint4*)&Vp[(size_t)(bh * 16 + d) * 4096 + n0 + j0];
    dst[0] = make_uint4(vv[0], vv[1], vv[2], vv[3]);
    dst[1] = make_uint4(vv[4], vv[5], vv[6], vv[7]);
}

// ---------------------------------------------------------------------------
// Fused per-ring kernel. WG (b,h,sp of 512 keys), 512 thr = 8 waves.
// Order: issue stage loads -> combine-merge r-1 (overlaps load latency) ->
// staging ds_writes -> GEMV+patch (LDS+global K/V) -> MFMA flash ring r ->
// in-LDS kh-merge -> 8-slice partials in [bh][q][slice] layout.
// TAIL: combine/feats only, grid 32 (b,sp).
// ---------------------------------------------------------------------------
template<bool TAIL>
__global__ __launch_bounds__(512, 2) void fusedRing(
    const float* __restrict__ x, const float* __restrict__ Wk0,
    const float* __restrict__ Wv0, const int* __restrict__ rings,
    const int* __restrict__ rsz, const ushort* __restrict__ Q0bf,
    ushort* __restrict__ Kp, ushort* __restrict__ Vp,
    float* __restrict__ pm2, float* __restrict__ pl2, float* __restrict__ po2,
    float* __restrict__ feats, int r)
{
    __shared__ ushort Kls[512 * 24];   // 24 KB, 48B rows (2-way banks)
    __shared__ ushort Vls[16 * 520];   // 16.6 KB, V^T rows stride 1040B
    __shared__ float  red[2 * 64 * 18];
    __shared__ float  outc[8 * 128];
    __shared__ int colsC[64], colsF[64], ownIdx[8];
    __shared__ int ownCnt;

    const int t = threadIdx.x, wgid = blockIdx.x;
    const int b  = TAIL ? (wgid >> 3) : (wgid >> 6);
    const int h  = TAIL ? 0 : ((wgid >> 3) & 7);
    const int sp = wgid & 7;
    const int bh = (b << 3) + h;
    const int keybase = sp << 9;
    const int n  = TAIL ? 0 : rsz[r];
    const int np = (r > 0) ? rsz[r - 1] : 0;

    if (t < 64) colsC[t] = (r > 0 && t < np) ? rings[(r-1)*64 + t] : -1;
    else if (t < 128) { int q = t - 64; colsF[q] = (!TAIL && q < n) ? rings[r*64 + q] : 0; }
    if (t == 0) ownCnt = 0;
    __syncthreads();                              // B1

    // ---- issue staging loads into regs ----
    uint4 kst[3], vst[2];
    if (!TAIL) {
        const ushort* kb = Kp + (size_t)(bh * 4096 + keybase) * 24;
#pragma unroll
        for (int i2 = 0; i2 < 3; ++i2)
            kst[i2] = *(const uint4*)(kb + (((i2 << 9) + t) << 3));
#pragma unroll
        for (int i2 = 0; i2 < 2; ++i2) {
            int idx = (i2 << 9) + t, d = idx >> 6, c8 = idx & 63;
            vst[i2] = *(const uint4*)(Vp + (size_t)(bh * 16 + d) * 4096
                                      + keybase + (c8 << 3));
        }
    }
    if (r > 0 && t < np) {
        int cq = colsC[t];
        if (cq >= keybase && cq < keybase + 512)
            ownIdx[atomicAdd(&ownCnt, 1)] = t;
    }
    __syncthreads();                              // B2
    const int cnt = (r > 0) ? ownCnt : 0;

    // ---- combine-merge ring r-1 (8-slice contiguous reads) ----
    if (cnt > 0) {
        const int bufp = (r - 1) & 1;
        const int slot = t >> 7, c = t & 127, hh = c >> 4, dd = c & 15;
#pragma unroll
        for (int pass = 0; pass < 2; ++pass) {
            int ow = (pass << 2) + slot;
            if (ow < cnt) {
                int j = ownIdx[ow], col = colsC[j];
                int pmb = (((bufp << 5) + (b << 3) + hh) << 9) + (j << 3);
                f32x4 m0 = *(const f32x4*)&pm2[pmb];
                f32x4 m1 = *(const f32x4*)&pm2[pmb + 4];
                float mstar = fmaxf(fmaxf(fmaxf(m0[0],m0[1]),fmaxf(m0[2],m0[3])),
                                    fmaxf(fmaxf(m1[0],m1[1]),fmaxf(m1[2],m1[3])));
                f32x4 l0 = *(const f32x4*)&pl2[pmb];
                f32x4 l1 = *(const f32x4*)&pl2[pmb + 4];
                int pob = ((((((bufp << 5) + (b << 3) + hh) << 6) + j) << 4) + dd) << 3;
                f32x4 o0 = *(const f32x4*)&po2[pob];
                f32x4 o1 = *(const f32x4*)&po2[pob + 4];
                float lst = 0.f, osum = 0.f;
#pragma unroll
                for (int s2 = 0; s2 < 4; ++s2) {
                    float e0 = __expf(m0[s2] - mstar);
                    lst += l0[s2] * e0; osum += o0[s2] * e0;
                    float e1 = __expf(m1[s2] - mstar);
                    lst += l1[s2] * e1; osum += o1[s2] * e1;
                }
                float outv = osum / lst + x[(size_t)((b << 7) + c) * 4096 + col];
                outc[(ow << 7) + c] = outv;
                if (h == 0) feats[(size_t)((b << 7) + c) * 4096 + col] = outv;
            }
        }
    }
    // ---- staging ds_writes (waits drain here, overlapped with merge) ----
    if (!TAIL) {
#pragma unroll
        for (int i2 = 0; i2 < 3; ++i2)
            *(uint4*)&Kls[(((i2 << 9) + t) << 3)] = kst[i2];
#pragma unroll
        for (int i2 = 0; i2 < 2; ++i2) {
            int idx = (i2 << 9) + t, d = idx >> 6, c8 = idx & 63;
            *(uint4*)&Vls[d * 520 + (c8 << 3)] = vst[i2];
        }
    }
    __syncthreads();                              // B3
    // ---- GEMV + patch (LDS + global) ----
    if (!TAIL && cnt > 0) {
        const int slot = t >> 7, rem = t & 127;
        const int task = rem >> 2, quarter = rem & 3;
        const int isV = task >> 4, dd = task & 15;
        const int row = (h << 4) + dd;
        const float* W = isV ? Wv0 : Wk0;
#pragma unroll
        for (int pass = 0; pass < 2; ++pass) {
            int ow = (pass << 2) + slot;
            if (ow < cnt) {
                int col = colsC[ownIdx[ow]];
                const f32x4* W4  = (const f32x4*)&W[(row << 7) + (quarter << 5)];
                const f32x4* oc4 = (const f32x4*)&outc[(ow << 7) + (quarter << 5)];
                float acc = 0.f;
#pragma unroll
                for (int c4 = 0; c4 < 8; ++c4) {
                    f32x4 wv = W4[c4], xv = oc4[c4];
                    acc += wv[0]*xv[0] + wv[1]*xv[1] + wv[2]*xv[2] + wv[3]*xv[3];
                }
                acc += __shfl_xor(acc, 1);
                acc += __shfl_xor(acc, 2);
                if (quarter == 0) {
                    ushort bfv = f2bf(acc);
                    int colL = col - keybase;
                    if (isV) { Vp[(size_t)(bh*16 + dd)*4096 + col] = bfv;
                               Vls[dd * 520 + colL] = bfv; }
                    else     { Kp[(size_t)(bh*4096 + col)*24 + dd] = bfv;
                               Kls[colL * 24 + dd] = bfv; }
                }
            }
        }
    }
    if (TAIL) return;
    __syncthreads();                              // B4

    // ---- MFMA flash ring r ----
    const int w = t >> 6, lane = t & 63;
    const int qt = w & 3, kh = w >> 2;
    const int lm = lane & 15, lg = lane >> 4;
    if (qt * 16 < n) {
        int cq = colsF[qt * 16 + lm];
        bhalf4 qf = *(const bhalf4*)&Q0bf[(size_t)(bh*4096 + cq)*16 + (lg << 2)];
        const int key0 = kh << 8;
        f32x4 sc[16];
#pragma unroll
        for (int kt = 0; kt < 16; ++kt) {
            bhalf4 kf = *(const bhalf4*)&Kls[(key0 + (kt << 4) + lm)*24 + (lg << 2)];
            f32x4 z = {0.f, 0.f, 0.f, 0.f};
            sc[kt] = __builtin_amdgcn_mfma_f32_16x16x16bf16_1k(kf, qf, z, 0, 0, 0);
        }
        float m = -3e38f;
#pragma unroll
        for (int kt = 0; kt < 16; ++kt)
            m = fmaxf(m, fmaxf(fmaxf(sc[kt][0], sc[kt][1]), fmaxf(sc[kt][2], sc[kt][3])));
        m = fmaxf(m, __shfl_xor(m, 16));
        m = fmaxf(m, __shfl_xor(m, 32));
        float lsum = 0.f;
        f32x4 oacc = {0.f, 0.f, 0.f, 0.f};
#pragma unroll
        for (int kt = 0; kt < 16; ++kt) {
            float p0 = __expf((sc[kt][0] - m) * 0.25f);
            float p1 = __expf((sc[kt][1] - m) * 0.25f);
            float p2 = __expf((sc[kt][2] - m) * 0.25f);
            float p3 = __expf((sc[kt][3] - m) * 0.25f);
            lsum += (p0 + p1) + (p2 + p3);
            bhalf4 pv;
            pv[0] = (short)f2bf(p0); pv[1] = (short)f2bf(p1);
            pv[2] = (short)f2bf(p2); pv[3] = (short)f2bf(p3);
            bhalf4 vf = *(const bhalf4*)&Vls[lm*520 + key0 + (kt << 4) + (lg << 2)];
            oacc = __builtin_amdgcn_mfma_f32_16x16x16bf16_1k(pv, vf, oacc, 0, 0, 0);
        }
        lsum += __shfl_xor(lsum, 16);
        lsum += __shfl_xor(lsum, 32);
#pragma unroll
        for (int reg = 0; reg < 4; ++reg)
            red[((kh << 6) + (qt << 4) + (lg << 2) + reg)*18 + lm] = oacc[reg];
        if (lg == 0) {
            red[((kh << 6) + (qt << 4) + lm)*18 + 16] = m * 0.25f;
            red[((kh << 6) + (qt << 4) + lm)*18 + 17] = lsum;
        }
    }
    __syncthreads();                              // B5
    // ---- kh-merge -> 8-slice partials [bh][q][slice] ----
    {
        const int buf = r & 1;
        int q = t >> 3, sub = t & 7;
        if (q < n) {
            float m0 = red[q*18 + 16],        l0v = red[q*18 + 17];
            float m1 = red[(64 + q)*18 + 16], l1v = red[(64 + q)*18 + 17];
            float M = fmaxf(m0, m1);
            float e0 = __expf(m0 - M), e1 = __expf(m1 - M);
            if (sub == 0) {
                pm2[(((buf << 5) + bh) << 9) + (q << 3) + sp] = M;
                pl2[(((buf << 5) + bh) << 9) + (q << 3) + sp] = l0v*e0 + l1v*e1;
            }
            int d0 = sub << 1;
#pragma unroll
            for (int dd = d0; dd < d0 + 2; ++dd) {
                float o = red[q*18 + dd]*e0 + red[(64 + q)*18 + dd]*e1;
                po2[((((((buf << 5) + bh) << 6) + q) << 4) + dd) << 3 | sp] = o;
            }
        }
    }
}

// ---------------------------------------------------------------------------
// Epilogues
// ---------------------------------------------------------------------------
__global__ __launch_bounds__(128) void epi1(
    const float* __restrict__ feats, const float* __restrict__ Wv0,
    const float* __restrict__ Wk1, const int* __restrict__ rings,
    float* __restrict__ Va, float* __restrict__ Kn)
{
    int b = blockIdx.x;
    int i = threadIdx.x;
    int anchor = rings[0];
    __shared__ float la[128];
    __shared__ float kk2[128];
    la[i] = feats[(size_t)((b << 7) + i) * 4096 + anchor];
    __syncthreads();
    float va = 0.f, k1 = 0.f;
    for (int c = 0; c < 128; ++c) {
        va += Wv0[i * 128 + c] * la[c];
        k1 += Wk1[i * 128 + c] * la[c];
    }
    Va[b * 128 + i] = va;
    kk2[i] = k1 * k1;
    __syncthreads();
    float ss = 0.f;
    int hb = i & ~15;
    for (int d = 0; d < 16; ++d) ss += kk2[hb + d];
    Kn[b * 128 + i] = k1 * rsqrtf(ss + 1e-8f);
}

__global__ __launch_bounds__(256) void epi2(
    const float* __restrict__ x, const float* __restrict__ Wq1,
    const float* __restrict__ Va, const float* __restrict__ Kn,
    float* __restrict__ scores)
{
    __shared__ float Wt[128 * 132];
    __shared__ float lxT[128 * 36];
    const int bid = blockIdx.x, t = threadIdx.x;
    const int b = bid >> 7, col0 = (bid & 127) << 5;
    for (int idx = t; idx < 128 * 128; idx += 256) {
        int o = idx >> 7, c = idx & 127;
        Wt[c*132 + o] = Wq1[idx];
    }
    for (int idx = t; idx < 128 * 32; idx += 256) {
        int c = idx >> 5, col = idx & 31;
        lxT[c*36 + col] = x[(size_t)((b << 7) + c) * 4096 + col0 + col] + Va[(b << 7) + c];
    }
    __syncthreads();
    const int og = t & 31, colg = t >> 5;
    const int o0 = og << 2, cl0 = colg << 2;
    float acc[4][4];
#pragma unroll
    for (int i = 0; i < 4; ++i)
#pragma unroll
        for (int j = 0; j < 4; ++j) acc[i][j] = 0.f;
    for (int c = 0; c < 128; ++c) {
        f32x4 wv = *(const f32x4*)&Wt[c*132 + o0];
        f32x4 xv = *(const f32x4*)&lxT[c*36 + cl0];
#pragma unroll
        for (int i = 0; i < 4; ++i)
#pragma unroll
            for (int j = 0; j < 4; ++j) acc[i][j] += wv[i] * xv[j];
    }
    float kn4[4];
#pragma unroll
    for (int i = 0; i < 4; ++i) kn4[i] = Kn[(b << 7) + o0 + i];
    float res[4];
#pragma unroll
    for (int j = 0; j < 4; ++j) {
        float ss = acc[0][j]*acc[0][j] + acc[1][j]*acc[1][j]
                 + acc[2][j]*acc[2][j] + acc[3][j]*acc[3][j];
        ss += __shfl_xor(ss, 1);
        ss += __shfl_xor(ss, 2);
        float rs = rsqrtf(ss + 1e-8f);
        float mp = (acc[0][j]*kn4[0] + acc[1][j]*kn4[1]
                  + acc[2][j]*kn4[2] + acc[3][j]*kn4[3]) * rs;
#pragma unroll
        for (int msk = 1; msk <= 16; msk <<= 1) mp += __shfl_xor(mp, msk);
        res[j] = 0.5f + mp * (1.0f / 16.0f);
    }
    if (og == 0) {
#pragma unroll
        for (int j = 0; j < 4; ++j)
            scores[(b << 12) + col0 + cl0 + j] = res[j];
    }
}

// ---------------------------------------------------------------------------
// Launcher: 1 init + 127 rings + 1 tail + 2 epilogues.
// ---------------------------------------------------------------------------
extern "C" void kernel_launch(void* const* d_in, const int* in_sizes, int n_in,
                              void* d_out, int out_size, void* d_ws, size_t ws_size,
                              hipStream_t stream) {
    const float* x   = (const float*)d_in[0];
    const float* Wq0 = (const float*)d_in[1];
    const float* Wk0 = (const float*)d_in[2];
    const float* Wv0 = (const float*)d_in[3];
    const float* Wq1 = (const float*)d_in[4];
    const float* Wk1 = (const float*)d_in[5];
    const int*   rings = (const int*)d_in[6];
    const int*   rsz   = (const int*)d_in[7];

    float* feats  = (float*)d_out;                 // (B,C,F)
    float* scores = feats + Bn * Cn * Fn;          // (B,F)

    float*  ws   = (float*)d_ws;
    ushort* Q0bf = (ushort*)(ws + OFF_Q0);
    ushort* Kp   = (ushort*)(ws + OFF_KP);
    ushort* Vp   = (ushort*)(ws + OFF_VP);
    float*  pm2  = ws + OFF_PM;
    float*  pl2  = ws + OFF_PL;
    float*  po2  = ws + OFF_PO;
    float*  Va   = ws + OFF_VA;
    float*  Kn   = ws + OFF_KN;

    initQKV<<<256, 512, 0, stream>>>(x, Wq0, Wk0, Wv0, Q0bf, Kp, Vp);

    for (int r = 0; r < NRINGS; ++r) {
        fusedRing<false><<<256, 512, 0, stream>>>(
            x, Wk0, Wv0, rings, rsz, Q0bf, Kp, Vp, pm2, pl2, po2, feats, r);
    }
    fusedRing<true><<<32, 512, 0, stream>>>(
        x, Wk0, Wv0, rings, rsz, Q0bf, Kp, Vp, pm2, pl2, po2, feats, NRINGS);

    epi1<<<Bn, 128, 0, stream>>>(feats, Wv0, Wk1, rings, Va, Kn);
    epi2<<<512, 256, 0, stream>>>(x, Wq1, Va, Kn, scores);
}